// Round 17
// baseline (121.903 us; speedup 1.0000x reference)
//
#include <hip/hip_runtime.h>

typedef unsigned int u32;
typedef unsigned short u16;
typedef unsigned long long u64;

typedef __attribute__((ext_vector_type(4))) float f32x4;
typedef __attribute__((ext_vector_type(8))) __bf16 bf16x8;
typedef __attribute__((ext_vector_type(8))) u16 u16x8;
typedef __attribute__((ext_vector_type(4))) u16 u16x4;

#define NB 256
#define ND 512
#define NC 100000
#define NSTR2 391              // stripes of 256 cols
#define CAP 131072             // u64 collect entries (1 MB)
#define THRC 0.15f             // collect threshold << neg_th (~0.188)
#define EXP2K 92.33248261689366f   // 64*log2(e)

// ---- ws layout (bytes) ----
#define OFF_EMBN  0            // u16 [256*512] = 262144
#define OFF_TGT   262144       // f32 [256]
#define OFF_SEXP  263168       // f32 [256]
#define OFF_AMAX  264192       // u64 [256] = 2048
#define OFF_SCAL  266240       // u32 [64] {topk, bufcnt, ...}
#define OFF_PART  266496       // f32 [256][800] = 819200
#define OFF_BUF   1085696      // u64 [CAP] = 1048576

__device__ __forceinline__ u32 ordkey(float f) {
  u32 u = __float_as_uint(f);
  return (u & 0x80000000u) ? ~u : (u | 0x80000000u);
}
__device__ __forceinline__ float inv_ordkey(u32 key) {
  u32 u = (key & 0x80000000u) ? (key & 0x7FFFFFFFu) : ~key;
  return __uint_as_float(u);
}
__device__ __forceinline__ u16 f2bf(float x) {  // RNE f32->bf16
  u32 u = __float_as_uint(x);
  return (u16)((u + 0x7FFFu + ((u >> 16) & 1u)) >> 16);
}
__device__ __forceinline__ float bf2f(u16 h) {
  return __uint_as_float(((u32)h) << 16);
}
// B-LDS chunk swizzle (proven R8/R12/R16)
__device__ __forceinline__ int bswz(int n) {
  return (n & 7) ^ ((n >> 3) & 7);
}

typedef const u32 __attribute__((address_space(1)))* gcp;
typedef u32 __attribute__((address_space(3)))* lsp;
__device__ __forceinline__ void gload16(const void* g, void* l) {
  __builtin_amdgcn_global_load_lds((gcp)g, (lsp)l, 16, 0, 0);
}

// ---------------- K0 (merged prep+tgt): embn row + tg[r] + ws clears --
__global__ __launch_bounds__(512) void k_tgt(const float* __restrict__ emb,
                                             const float* __restrict__ kern,
                                             const int* __restrict__ lab,
                                             u16* __restrict__ embn,
                                             float* __restrict__ tgtws,
                                             u64* __restrict__ amax_g,
                                             u32* __restrict__ scal) {
  __shared__ float sd[512], sq[512];
  const int r = blockIdx.x, t = threadIdx.x;
  if (t == 0) amax_g[r] = 0ull;
  if (r == 0 && t < 64) scal[t] = 0u;
  const float e = emb[r * ND + t];
  sd[t] = e * e;
  __syncthreads();
  for (int st = 256; st > 0; st >>= 1) {
    if (t < st) sd[t] += sd[t + st];
    __syncthreads();
  }
  const float rinv = 1.0f / sqrtf(sd[0]);
  __syncthreads();
  const u16 aq = f2bf(e * rinv);
  embn[r * ND + t] = aq;
  const float a = bf2f(aq);
  const int lb = lab[r];
  const float x = kern[(size_t)t * NC + lb];
  const float xb = bf2f(f2bf(x));        // same quantization as GEMM B path
  sd[t] = a * xb; sq[t] = x * x;
  __syncthreads();
  for (int st = 256; st > 0; st >>= 1) {
    if (t < st) { sd[t] += sd[t + st]; sq[t] += sq[t + st]; }
    __syncthreads();
  }
  if (t == 0) {
    float v = sd[0] / sqrtf(sq[0]);
    tgtws[r] = fminf(fmaxf(v, -1.0f), 1.0f);
  }
}

// ---------------- K1: FUSED bf16 MFMA GEMM, 1KB-segment edition -------
// tile M=256 x N=256, BK=64, 1024 thr = 16 waves (4Mx4N), wave 64x64,
// acc[4][4]. B: wave w reads 4 consecutive k-rows; per k-row its 64
// lanes span 256 cols via float4 = 1KB CONTIGUOUS segments (segment-
// length hypothesis: 256B->0.69, 512B->0.9 TB/s; predict 1KB->1.2+).
// Each thread: 4 k x 4 cols -> in-reg transpose -> 4x u16x4 k-contig
// writes into Bs[n][72-pad]. A: proven gload_lds XOR-preswizzled path
// (2 inst/thread). Blocks halve (391) -> A request traffic halves.
// Epilogue aliased over As/Bs. Chunked-XCD bijective stripe map.
__global__ __launch_bounds__(1024, 4) void k_gemm(const float* __restrict__ kern,
                                                  const u16* __restrict__ embn,
                                                  const int* __restrict__ lab,
                                                  const float* __restrict__ tgtws,
                                                  u32* __restrict__ scal,
                                                  u64* __restrict__ buf,
                                                  u64* __restrict__ amax_g,
                                                  float* __restrict__ sexp_part) {
  __shared__ char smem[69632];
  u16* As = (u16*)smem;                        // [256][64] linear = 32768 B
  u16* Bs = (u16*)(smem + 32768);              // [256][72-pad] = 36864 B
  // epilogue aliases (over As, dead after K-loop):
  float* colp = (float*)smem;                  // [16][256] = 16384 B
  float* sexp_q = (float*)(smem + 16384);      // [4][256] = 4096 B
  u64* amax_lds = (u64*)(smem + 20480);        // [256] = 2048 B
  u32* swcnt = (u32*)(smem + 22528);           // [16]

  const int tid = threadIdx.x;
  const int lane = tid & 63;
  const int w = tid >> 6;                      // wave 0..15
  const int mbase = (w >> 2) * 64, nbase = (w & 3) * 64;
  const int l15 = lane & 15, g = lane >> 4;
  // chunked-XCD bijective stripe map: 391 stripes over 8 classes
  const int bid = blockIdx.x;
  const int x8 = bid & 7, idx = bid >> 3;
  const int scnt = (x8 < 7) ? 49 : 48;
  if (idx >= scnt) return;                     // 1 pad block
  const int p = (x8 < 7) ? (x8 * 49 + idx) : (343 + idx);
  const int cblk = p * 256;

  f32x4 acc[4][4];
  #pragma unroll
  for (int i = 0; i < 4; ++i)
    #pragma unroll
    for (int j = 0; j < 4; ++j) acc[i][j] = (f32x4){0.f, 0.f, 0.f, 0.f};

  // A staging: slot = tid + i*1024 -> row = i*128 + (tid>>3), chunk = tid&7
  const int sm = tid >> 3;
  const int sx = ((tid & 7) ^ (sm & 7)) * 8;   // source pre-swizzle
  const u16* a_src[2];
  #pragma unroll
  for (int i = 0; i < 2; ++i)
    a_src[i] = embn + (size_t)(sm + i * 128) * ND + sx;
  const int a_dst = w * 512;                   // u16 units; + i*8192

  // B staging: wave w owns k-rows w*4..w*4+3; lane -> col quad lane*4
  const int cq = lane * 4;
  int gcq = cblk + cq;
  if (gcq > NC - 4) gcq = NC - 4;              // clamp; masked in epilogue
  const float* b_src = kern + (size_t)(w * 4) * NC + gcq;
  // LDS write positions for the 4 cols (k-chunk c8 = w>>1, half = w&1)
  u16* bdst[4];
  #pragma unroll
  for (int j = 0; j < 4; ++j) {
    const int n = cq + j;
    bdst[j] = Bs + n * 72 + (((w >> 1) ^ bswz(n)) * 8 + (w & 1) * 4);
  }
  float ss0 = 0.f, ss1 = 0.f, ss2 = 0.f, ss3 = 0.f;

  for (int ks = 0; ks < 8; ++ks) {
    const int k0 = ks * 64;
    // B: 4 x float4 at consecutive k-rows (1KB/wave segments)
    float4 f[4];
    #pragma unroll
    for (int i = 0; i < 4; ++i)
      f[i] = *(const float4*)(b_src + (size_t)(k0 + i) * NC);
    // A: 2 x global_load_lds(16B)
    #pragma unroll
    for (int i = 0; i < 2; ++i) gload16(a_src[i] + k0, As + i * 8192 + a_dst);
    // B: in-reg transpose + convert + ssq + 4x b64 k-contig LDS writes
    ss0 += f[0].x*f[0].x + f[1].x*f[1].x + f[2].x*f[2].x + f[3].x*f[3].x;
    ss1 += f[0].y*f[0].y + f[1].y*f[1].y + f[2].y*f[2].y + f[3].y*f[3].y;
    ss2 += f[0].z*f[0].z + f[1].z*f[1].z + f[2].z*f[2].z + f[3].z*f[3].z;
    ss3 += f[0].w*f[0].w + f[1].w*f[1].w + f[2].w*f[2].w + f[3].w*f[3].w;
    u16x4 q0 = { f2bf(f[0].x), f2bf(f[1].x), f2bf(f[2].x), f2bf(f[3].x) };
    u16x4 q1 = { f2bf(f[0].y), f2bf(f[1].y), f2bf(f[2].y), f2bf(f[3].y) };
    u16x4 q2 = { f2bf(f[0].z), f2bf(f[1].z), f2bf(f[2].z), f2bf(f[3].z) };
    u16x4 q3 = { f2bf(f[0].w), f2bf(f[1].w), f2bf(f[2].w), f2bf(f[3].w) };
    *(u16x4*)bdst[0] = q0; *(u16x4*)bdst[1] = q1;
    *(u16x4*)bdst[2] = q2; *(u16x4*)bdst[3] = q3;
    __syncthreads();                       // tiles ready
    #pragma unroll
    for (int kf = 0; kf < 2; ++kf) {
      bf16x8 bfr[4], afr[4];
      #pragma unroll
      for (int nf = 0; nf < 4; ++nf) {
        const int n = nbase + nf * 16 + l15;
        bfr[nf] = *(const bf16x8*)(Bs + n * 72 + (((kf * 4 + g) ^ bswz(n)) * 8));
      }
      #pragma unroll
      for (int mf = 0; mf < 4; ++mf) {
        const int m = mbase + mf * 16 + l15;
        afr[mf] = *(const bf16x8*)(As + m * 64 + ((kf * 32 + g * 8) ^ ((m & 7) << 3)));
      }
      #pragma unroll
      for (int mf = 0; mf < 4; ++mf)
        #pragma unroll
        for (int nf = 0; nf < 4; ++nf)
          acc[mf][nf] = __builtin_amdgcn_mfma_f32_16x16x32_bf16(afr[mf], bfr[nf], acc[mf][nf], 0, 0, 0);
    }
    __syncthreads();                       // protect LDS before re-stage
  }

  // ---- column ssq: 16 kq partials per col, deterministic reduce ----
  colp[w * 256 + cq + 0] = ss0; colp[w * 256 + cq + 1] = ss1;
  colp[w * 256 + cq + 2] = ss2; colp[w * 256 + cq + 3] = ss3;
  if (tid < 256) amax_lds[tid] = 0ull;
  __syncthreads();
  if (tid < 256) {
    float s = 0.f;
    #pragma unroll
    for (int q = 0; q < 16; ++q) s += colp[q * 256 + tid];
    colp[tid] = s;
  }
  __syncthreads();

  // ---- fused epilogue: stats straight from accumulators ----
  float cinv[4];
  #pragma unroll
  for (int nf = 0; nf < 4; ++nf) {
    const int nl = nbase + nf * 16 + l15;
    cinv[nf] = ((cblk + nl) < NC) ? (1.0f / sqrtf(colp[nl])) : 0.f;
  }
  u32 cnt_t = 0;
  #pragma unroll
  for (int mf = 0; mf < 4; ++mf) {
    #pragma unroll
    for (int r = 0; r < 4; ++r) {
      const int row = mbase + mf * 16 + g * 4 + r;
      const float tg = tgtws[row];
      const int lb = lab[row];
      float e = 0.f; u64 pk = 0ull;
      #pragma unroll
      for (int nf = 0; nf < 4; ++nf) {
        const int c = cblk + nbase + nf * 16 + l15;
        if (c < NC) {
          float v = acc[mf][nf][r] * cinv[nf];
          v = fminf(fmaxf(v, -1.0f), 1.0f);
          e += exp2f(EXP2K * v);
          const u64 pq = ((u64)ordkey(v) << 32) | (u32)(0xFFFFFFFFu - (u32)c);
          if (pq > pk) pk = pq;
          if (c != lb) {
            if (v > tg) cnt_t++;
            else if (v >= THRC) {
              u32 pos = atomicAdd(&scal[1], 1u);
              if (pos < CAP) buf[pos] = ((u64)ordkey(v) << 32) | (u32)row;
            }
          }
        }
      }
      #pragma unroll
      for (int m = 1; m < 16; m <<= 1) {
        e += __shfl_xor(e, m, 64);
        u64 o = __shfl_xor(pk, m, 64);
        if (o > pk) pk = o;
      }
      if (l15 == 0) {
        sexp_q[(w & 3) * 256 + row] = e;    // each (wn,row) written exactly once
        atomicMax(&amax_lds[row], pk);      // integer max: order-independent
      }
    }
  }
  #pragma unroll
  for (int m = 1; m < 64; m <<= 1) cnt_t += __shfl_xor(cnt_t, m, 64);
  if (lane == 0) swcnt[w] = cnt_t;
  __syncthreads();
  if (tid == 0) {
    u32 s = 0;
    #pragma unroll
    for (int i = 0; i < 16; ++i) s += swcnt[i];
    atomicAdd(&scal[0], s);
  }
  if (tid < 256) {
    sexp_part[(size_t)tid * 800 + p] =
        (sexp_q[tid] + sexp_q[256 + tid]) + (sexp_q[512 + tid] + sexp_q[768 + tid]);
    atomicMax(&amax_g[tid], amax_lds[tid]);
  }
}

// ---------------- K2: deterministic per-row sexp reduction ------------
__global__ void k_reduce(const float* __restrict__ part, float* __restrict__ sexpws) {
  __shared__ float s[256];
  const int r = blockIdx.x, t = threadIdx.x;
  float a = 0.f;
  for (int b = t; b < NSTR2; b += 256) a += part[(size_t)r * 800 + b];
  s[t] = a;
  __syncthreads();
  for (int st = 128; st > 0; st >>= 1) { if (t < st) s[t] += s[t + st]; __syncthreads(); }
  if (t == 0) sexpws[r] = s[0];
}

// ---------------- K3: finisher (1 block): select th + stats + loss ----
__global__ __launch_bounds__(1024) void k_finish(const u64* __restrict__ buf,
                                                 const u32* __restrict__ scal,
                                                 const int* __restrict__ lab,
                                                 const float* __restrict__ tgtws,
                                                 const float* __restrict__ sexpws,
                                                 const u64* __restrict__ amax_g,
                                                 float* __restrict__ out) {
  __shared__ u32 hist[4096];
  __shared__ u32 s[1024], cs[1024];
  __shared__ u32 sb1, sr1, sb2, sr2, sthkey, lcnt;
  __shared__ u64 lbuf[512];
  __shared__ float rl[256], ra[256];
  const int tid = threadIdx.x;
  const int n = (int)min(scal[1], (u32)CAP);
  const int topk = (int)scal[0];
  int a = 25599744 - topk; if (a < 0) a = 0;               // B*(C-1)
  int k = (int)ceilf((1.0f / 99999.0f) * (float)a);        // mirror ref f32 math
  if (k < 1) k = 1;

  if (tid == 0) { sb1 = 0; sr1 = 1; sb2 = 0; sr2 = 1; lcnt = 0; }
  // ---- level 1: key bits 31..20 ----
  for (int i = tid; i < 4096; i += 1024) hist[i] = 0;
  __syncthreads();
  for (int i = tid; i < n; i += 1024) atomicAdd(&hist[(u32)(buf[i] >> 52)], 1u);
  __syncthreads();
  {
    u32 h[4]; u32 c = 0;
    #pragma unroll
    for (int j = 0; j < 4; ++j) { h[j] = hist[tid * 4 + j]; c += h[j]; }
    cs[tid] = c; s[tid] = c;
    __syncthreads();
    for (int off = 1; off < 1024; off <<= 1) {
      u32 v = (tid + off < 1024) ? s[tid + off] : 0u;
      __syncthreads(); s[tid] += v; __syncthreads();
    }
    u32 incl = s[tid], excl = incl - cs[tid];
    if ((int)excl < k && (int)incl >= k) {
      u32 cum = excl;
      for (int j = 3; j >= 0; --j) {
        cum += h[j];
        if ((int)cum >= k) { sb1 = tid * 4 + j; sr1 = (u32)k - (cum - h[j]); break; }
      }
    }
  }
  __syncthreads();
  const u32 b1 = sb1, r1 = sr1;
  // ---- level 2: key bits 19..8 ----
  for (int i = tid; i < 4096; i += 1024) hist[i] = 0;
  __syncthreads();
  for (int i = tid; i < n; i += 1024) {
    u32 key = (u32)(buf[i] >> 32);
    if ((key >> 20) == b1) atomicAdd(&hist[(key >> 8) & 4095u], 1u);
  }
  __syncthreads();
  {
    u32 h[4]; u32 c = 0;
    #pragma unroll
    for (int j = 0; j < 4; ++j) { h[j] = hist[tid * 4 + j]; c += h[j]; }
    cs[tid] = c; s[tid] = c;
    __syncthreads();
    for (int off = 1; off < 1024; off <<= 1) {
      u32 v = (tid + off < 1024) ? s[tid + off] : 0u;
      __syncthreads(); s[tid] += v; __syncthreads();
    }
    u32 incl = s[tid], excl = incl - cs[tid];
    if (excl < r1 && incl >= r1) {
      u32 cum = excl;
      for (int j = 3; j >= 0; --j) {
        cum += h[j];
        if (cum >= r1) { sb2 = tid * 4 + j; sr2 = r1 - (cum - h[j]); break; }
      }
    }
  }
  __syncthreads();
  const u32 b2 = sb2, r2 = sr2;
  // ---- level 3: key bits 7..0 ----
  for (int i = tid; i < 256; i += 1024) hist[i] = 0;
  __syncthreads();
  const u32 pfx = (b1 << 12) | b2;
  for (int i = tid; i < n; i += 1024) {
    u32 key = (u32)(buf[i] >> 32);
    if ((key >> 8) == pfx) atomicAdd(&hist[key & 255u], 1u);
  }
  __syncthreads();
  if (tid == 0) {
    u32 cum = 0, b3 = 0;
    for (int j = 255; j >= 0; --j) { cum += hist[j]; if (cum >= r2) { b3 = (u32)j; break; } }
    sthkey = (b1 << 20) | (b2 << 8) | b3;
  }
  __syncthreads();
  const u32 thk = sthkey;
  // ---- collect strictly-greater entries (k-1 < 512 of them) ----
  for (int i = tid; i < n; i += 1024) {
    u64 e = buf[i];
    if ((u32)(e >> 32) > thk) { u32 pq = atomicAdd(&lcnt, 1u); if (pq < 512) lbuf[pq] = e; }
  }
  __syncthreads();
  const int m = (int)min(lcnt, 512u);
  if (tid < 256) {
    const int r = tid;
    int cnt = 0; float ssq = 0.f;
    for (int j = 0; j < m; ++j) {
      u64 e = lbuf[j];
      if ((u32)(e & 0xFFFFFFFFu) == (u32)r) {
        float v = inv_ordkey((u32)(e >> 32));
        cnt++; ssq += v * v;
      }
    }
    const float tg = tgtws[r];
    const float times = fmaxf((float)cnt, 1.0f);
    const float nm = ssq / times;
    const float tgm = (tg - 0.4f) - (1.0f + tg) * nm;
    const float sexp = sexpws[r] - exp2f(EXP2K * tg) + exp2f(EXP2K * tgm);
    rl[r] = logf(sexp) - 64.0f * tgm;
    const u32 acol = 0xFFFFFFFFu - (u32)(amax_g[r] & 0xFFFFFFFFu);
    ra[r] = (acol == (u32)lab[r]) ? 1.0f : 0.0f;
  }
  __syncthreads();
  for (int st = 128; st > 0; st >>= 1) {
    if (tid < st) { rl[tid] += rl[tid + st]; ra[tid] += ra[tid + st]; }
    __syncthreads();
  }
  if (tid == 0) { out[0] = rl[0] * (1.0f / 256.0f); out[1] = ra[0] * (1.0f / 256.0f); }
}

extern "C" void kernel_launch(void* const* d_in, const int* in_sizes, int n_in,
                              void* d_out, int out_size, void* d_ws, size_t ws_size,
                              hipStream_t stream) {
  const float* emb = (const float*)d_in[0];
  const int* lab = (const int*)d_in[1];
  const float* kern = (const float*)d_in[2];
  float* out = (float*)d_out;
  char* ws = (char*)d_ws;

  u16* embn = (u16*)(ws + OFF_EMBN);
  float* tgtws = (float*)(ws + OFF_TGT);
  float* sexpws = (float*)(ws + OFF_SEXP);
  u64* amax_g = (u64*)(ws + OFF_AMAX);
  u32* scal = (u32*)(ws + OFF_SCAL);   // [0]=topk [1]=bufcnt
  float* part = (float*)(ws + OFF_PART);
  u64* buf = (u64*)(ws + OFF_BUF);

  k_tgt<<<NB, 512, 0, stream>>>(emb, kern, lab, embn, tgtws, amax_g, scal);
  k_gemm<<<392, 1024, 0, stream>>>(kern, embn, lab, tgtws, scal, buf, amax_g, part);
  k_reduce<<<NB, 256, 0, stream>>>(part, sexpws);
  k_finish<<<1, 1024, 0, stream>>>(buf, scal, lab, tgtws, sexpws, amax_g, out);
}